// Round 1
// baseline (253.262 us; speedup 1.0000x reference)
//
#include <hip/hip_runtime.h>
#include <hip/hip_bf16.h>
#include <stdint.h>

#define BDIM 4
#define LDIM 128
#define DDIM 256
#define CDIM 512
#define EPSLN 1e-5f
#define NE (BDIM * LDIM * LDIM)
#define JT 4            // j-values per k_main block

typedef float f32x4 __attribute__((ext_vector_type(4)));
typedef short s16x8 __attribute__((ext_vector_type(8)));
typedef int i32x4 __attribute__((ext_vector_type(4)));

__device__ __forceinline__ unsigned short f2bf(float f) {
    unsigned u = __builtin_bit_cast(unsigned, f);
    u += 0x7fffu + ((u >> 16) & 1u);   // RNE (no NaNs in this data)
    return (unsigned short)(u >> 16);
}

// packed f32x2 -> bf16x2 (v_cvt_pk_bf16_f32 on gfx950), a in low 16, b in high
__device__ __forceinline__ unsigned pk_bf16(float a, float b) {
    union { __hip_bfloat162 h; unsigned u; } cv;
    cv.h = __float22bfloat162_rn(make_float2(a, b));
    return cv.u;
}

// ---------------------------------------------------------------------------
// Transpose + cast BOTH inputs: [B][L][D] f32 -> [B][D][L] f32 and bf16.
// grid (D/32, L/32, 2*B), block 256.  z: b = z&3, sel = z>>2 (0=value,1=query)
// (unchanged from v238 — not the suspected bottleneck; isolate k_main change)
// ---------------------------------------------------------------------------
__global__ __launch_bounds__(256) void k_transpose(const float* __restrict__ query,
                                                   const float* __restrict__ value,
                                                   float* __restrict__ Qt32,
                                                   float* __restrict__ Vt32,
                                                   unsigned short* __restrict__ Qt16,
                                                   unsigned short* __restrict__ Vt16) {
    __shared__ float tile[32][33];
    const int d0 = blockIdx.x * 32, k0 = blockIdx.y * 32;
    const int b = blockIdx.z & 3, sel = blockIdx.z >> 2;
    const float* src = sel ? query : value;
    float* dst32 = sel ? Qt32 : Vt32;
    unsigned short* dst16 = sel ? Qt16 : Vt16;
    const int tx = threadIdx.x & 31, ty = threadIdx.x >> 5;
#pragma unroll
    for (int jj = 0; jj < 4; ++jj) {
        int r = ty + jj * 8;
        tile[r][tx] = src[((size_t)(b * LDIM + k0 + r)) * DDIM + d0 + tx];
    }
    __syncthreads();
#pragma unroll
    for (int jj = 0; jj < 4; ++jj) {
        int r = ty + jj * 8;
        float v = tile[tx][r];
        size_t o = ((size_t)(b * DDIM + d0 + r)) * LDIM + k0 + tx;
        dst32[o] = v;
        dst16[o] = f2bf(v);
    }
}

// ---------------------------------------------------------------------------
// Fused Gram + E-build.  which 0:QV->E1  1:VV->E2  2:QQ->E1q  3:VQ->E2q
// E = exp(0.5*gram - rowmax_over_unmasked), 0 at masked keys.
// grid (8 i-tiles of 16 rows, 4 which, B), block 128 (2 waves).
// (unchanged from v238)
// ---------------------------------------------------------------------------
__global__ __launch_bounds__(128) void k_gram_e(const float* __restrict__ Qt,
                                                const float* __restrict__ Vt,
                                                const int* __restrict__ mask,
                                                float* __restrict__ Es) {
    const int it = blockIdx.x, which = blockIdx.y, b = blockIdx.z;
    const float* Xt;
    const float* Yt;
    if (which == 0)      { Xt = Qt; Yt = Vt; }
    else if (which == 1) { Xt = Vt; Yt = Vt; }
    else if (which == 2) { Xt = Qt; Yt = Qt; }
    else                 { Xt = Vt; Yt = Qt; }

    const int i0 = it * 16 + ((threadIdx.x >> 5) << 2);
    const int kt = (threadIdx.x & 31) << 2;
    const float* xb = Xt + (size_t)b * DDIM * LDIM + i0;
    const float* yb = Yt + (size_t)b * DDIM * LDIM + kt;

    float acc[4][4] = {};
#pragma unroll 8
    for (int c = 0; c < DDIM; ++c) {
        f32x4 xv = *(const f32x4*)(xb + (size_t)c * LDIM);
        f32x4 yv = *(const f32x4*)(yb + (size_t)c * LDIM);
#pragma unroll
        for (int ii = 0; ii < 4; ++ii)
#pragma unroll
            for (int kk = 0; kk < 4; ++kk)
                acc[ii][kk] += xv[ii] * yv[kk];
    }

    const i32x4 mv = *(const i32x4*)(mask + b * LDIM + kt);
    float* Eg = Es + (size_t)which * NE + (size_t)b * (LDIM * LDIM);
#pragma unroll
    for (int ii = 0; ii < 4; ++ii) {
        float lg[4];
        float mx = -3.0e38f;
#pragma unroll
        for (int kk = 0; kk < 4; ++kk) {
            lg[kk] = 0.5f * acc[ii][kk];
            if (mv[kk] != 0) mx = fmaxf(mx, lg[kk]);
        }
#pragma unroll
        for (int o = 16; o >= 1; o >>= 1) mx = fmaxf(mx, __shfl_xor(mx, o, 64));
        f32x4 r;
#pragma unroll
        for (int kk = 0; kk < 4; ++kk) r[kk] = (mv[kk] != 0) ? __expf(lg[kk] - mx) : 0.0f;
        *(f32x4*)(Eg + (size_t)(i0 + ii) * LDIM + kt) = r;
    }
}

// ---------------------------------------------------------------------------
// Main fused kernel v2.  grid (4 i-tiles, 32 j-tiles, B), block 256 (4 waves),
// JT=4 j per block -> 512 blocks = exactly 2 resident/CU, no tail.
// Wave wv: path = wv>>1 (0: attn@V cols 0..255, 1: attn_q@Q cols 256..511),
//          nh = wv&1 (128-col half). B-frags register-resident ONCE per 4 j
// (B-frag + E1-row L2 traffic /4 vs v238).
// Epilogue: register-direct LN. Per-wave partial sum/sumsq via shfl over the
// 16-lane col group, 1 KB cross-wave LDS reduce (double-buffered by jj&1 ->
// single barrier per j), affine+mask in-register, dword stores: 16 lanes =
// aligned 64B segment, adjacent nt pairs cover full 128B lines (no RMW).
// Stores of jj drain under MFMA of jj+1 (no stage, no barrier-fenced tail).
// MFMA 16x16x32 bf16: A[m=lane&15][k=quad*8+u], B[k][n=lane&15],
//                     C row = quad*4+reg, col = lane&15.  (verified R1)
// LDS ~77 KB (P x4 j 69.6K + wln/bln 4K + zinv 1K + red 2K) <= 80K: 2 blk/CU.
// VGPR peak ~235 (bfr 128 + acc 64 + epilogue temps) <= 256: no spill.
// ---------------------------------------------------------------------------
__global__ __launch_bounds__(256, 2) void k_main(const float* __restrict__ E1,
                                                 const unsigned short* __restrict__ Vt16,
                                                 const unsigned short* __restrict__ Qt16,
                                                 const int* __restrict__ mask,
                                                 const float* __restrict__ nw,
                                                 const float* __restrict__ nb,
                                                 float* __restrict__ out) {
    __shared__ __align__(16) unsigned short P_s[JT][2][32][136];  // [jj][path][row][k]
    __shared__ float wln[CDIM], bln[CDIM];
    __shared__ float zinv_s[JT][2][32];
    __shared__ __align__(16) float red[2][32][4][2];              // [jj&1][row][wave][s1,s2]
    __shared__ float maskv[32];

    const int tid = threadIdx.x;
    const int i0 = blockIdx.x * 32;
    const int j0 = blockIdx.y * JT;
    const int b = blockIdx.z;

    const int lane = tid & 63;
    const int q = lane >> 4;
    const int l15 = lane & 15;
    const int wv = tid >> 6;
    const int path = wv >> 1;
    const int nh = wv & 1;

    const float* E2 = E1 + NE;
    const float* E1q = E1 + 2 * NE;
    const float* E2q = E1 + 3 * NE;

    wln[tid] = nw[tid]; wln[tid + 256] = nw[tid + 256];
    bln[tid] = nb[tid]; bln[tid + 256] = nb[tid + 256];
    if (tid < 32) maskv[tid] = (mask[b * LDIM + i0 + tid] != 0) ? 1.0f : 0.0f;

    // B-fragment preload: this wave's 128-col x 128-k quarter (L2). Once per 4 j.
    const unsigned short* bsrc = (path ? Qt16 : Vt16) +
                                 (size_t)b * DDIM * LDIM + (size_t)(nh * 128) * LDIM;
    s16x8 bfr[8][4];
#pragma unroll
    for (int nt = 0; nt < 8; ++nt)
#pragma unroll
        for (int kc = 0; kc < 4; ++kc)
            bfr[nt][kc] = *(const s16x8*)(bsrc + (size_t)(nt * 16 + l15) * LDIM + kc * 32 + q * 8);

    // ---- phase A: P[jj] = E1 (.) E2[j0+jj] (packed bf16 -> LDS) + f32 Z sums
    {
        const int m = tid >> 3;
        const int k0 = (tid & 7) * 16;
        const float* e1 = E1 + ((size_t)(b * LDIM + i0 + m)) * LDIM + k0;
        const float* e1q = E1q + ((size_t)(b * LDIM + i0 + m)) * LDIM + k0;
        const float* e2 = E2 + ((size_t)(b * LDIM + j0)) * LDIM + k0;
        const float* e2q = E2q + ((size_t)(b * LDIM + j0)) * LDIM + k0;
        float s[JT] = {}, sq[JT] = {};
#pragma unroll
        for (int u4 = 0; u4 < 16; u4 += 4) {
            const f32x4 a = *(const f32x4*)(e1 + u4);
            const f32x4 aq = *(const f32x4*)(e1q + u4);
#pragma unroll
            for (int jj = 0; jj < JT; ++jj) {
                const f32x4 c = *(const f32x4*)(e2 + jj * LDIM + u4);
                const f32x4 cq = *(const f32x4*)(e2q + jj * LDIM + u4);
                const float p0 = a[0] * c[0], p1 = a[1] * c[1];
                const float p2 = a[2] * c[2], p3 = a[3] * c[3];
                const float r0 = aq[0] * cq[0], r1 = aq[1] * cq[1];
                const float r2 = aq[2] * cq[2], r3 = aq[3] * cq[3];
                s[jj] += (p0 + p1) + (p2 + p3);
                sq[jj] += (r0 + r1) + (r2 + r3);
                uint2 wp; wp.x = pk_bf16(p0, p1); wp.y = pk_bf16(p2, p3);
                uint2 wq2; wq2.x = pk_bf16(r0, r1); wq2.y = pk_bf16(r2, r3);
                *(uint2*)&P_s[jj][0][m][k0 + u4] = wp;
                *(uint2*)&P_s[jj][1][m][k0 + u4] = wq2;
            }
        }
#pragma unroll
        for (int jj = 0; jj < JT; ++jj) {
            float s_ = s[jj], sq_ = sq[jj];
            s_ += __shfl_xor(s_, 1, 64); s_ += __shfl_xor(s_, 2, 64); s_ += __shfl_xor(s_, 4, 64);
            sq_ += __shfl_xor(sq_, 1, 64); sq_ += __shfl_xor(sq_, 2, 64); sq_ += __shfl_xor(sq_, 4, 64);
            if ((tid & 7) == 0) { zinv_s[jj][0][m] = 1.0f / s_; zinv_s[jj][1][m] = 1.0f / sq_; }
        }
    }
    __syncthreads();

    // wave-constant LN affine coefficients for this wave's 128 cols
    const int c0 = path * 256 + nh * 128 + l15;
    float wreg[8], breg[8];
#pragma unroll
    for (int nt = 0; nt < 8; ++nt) { wreg[nt] = wln[c0 + nt * 16]; breg[nt] = bln[c0 + nt * 16]; }

    // ---- per-j: MFMA -> register LN -> direct store ----
#pragma unroll 1
    for (int jj = 0; jj < JT; ++jj) {
        f32x4 acc[2][8];
#pragma unroll
        for (int mt = 0; mt < 2; ++mt)
#pragma unroll
            for (int nt = 0; nt < 8; ++nt) acc[mt][nt] = (f32x4){0.f, 0.f, 0.f, 0.f};

        const unsigned short(*As)[136] = P_s[jj][path];
#pragma unroll
        for (int kc = 0; kc < 4; ++kc) {
            const s16x8 a0 = *(const s16x8*)&As[l15][kc * 32 + q * 8];
            const s16x8 a1 = *(const s16x8*)&As[16 + l15][kc * 32 + q * 8];
#pragma unroll
            for (int nt = 0; nt < 8; ++nt) {
                acc[0][nt] = __builtin_amdgcn_mfma_f32_16x16x32_bf16(a0, bfr[nt][kc], acc[0][nt], 0, 0, 0);
                acc[1][nt] = __builtin_amdgcn_mfma_f32_16x16x32_bf16(a1, bfr[nt][kc], acc[1][nt], 0, 0, 0);
            }
        }

        // normalize by Z in-register, per-wave 128-col partial sums per row
        const int rb = jj & 1;
#pragma unroll
        for (int mt = 0; mt < 2; ++mt)
#pragma unroll
            for (int reg = 0; reg < 4; ++reg) {
                const int row = mt * 16 + q * 4 + reg;
                const float zv = zinv_s[jj][path][row];
                float s1 = 0.f, s2 = 0.f;
#pragma unroll
                for (int nt = 0; nt < 8; ++nt) {
                    const float v = acc[mt][nt][reg] * zv;
                    acc[mt][nt][reg] = v;
                    s1 += v; s2 += v * v;
                }
#pragma unroll
                for (int o = 1; o <= 8; o <<= 1) {
                    s1 += __shfl_xor(s1, o, 64);
                    s2 += __shfl_xor(s2, o, 64);
                }
                if (l15 == 0) { red[rb][row][wv][0] = s1; red[rb][row][wv][1] = s2; }
            }
        __syncthreads();   // red[rb] complete (also >=1 barrier between reuse of rb)

        // finalize LN per row, apply affine+mask, store this wave's 128 cols
#pragma unroll
        for (int mt = 0; mt < 2; ++mt)
#pragma unroll
            for (int reg = 0; reg < 4; ++reg) {
                const int row = mt * 16 + q * 4 + reg;
                const f32x4 r0 = *(const f32x4*)&red[rb][row][0][0];
                const f32x4 r1 = *(const f32x4*)&red[rb][row][2][0];
                const float s1t = (r0[0] + r0[2]) + (r1[0] + r1[2]);
                const float s2t = (r0[1] + r0[3]) + (r1[1] + r1[3]);
                const float mean = s1t * (1.0f / 512.0f);
                const float var = s2t * (1.0f / 512.0f) - mean * mean;
                const float rstd = rsqrtf(var + EPSLN);
                const float mf = maskv[row];
                float* orow = out + (((size_t)(b * LDIM + i0 + row)) * LDIM + (j0 + jj)) * CDIM + c0;
#pragma unroll
                for (int nt = 0; nt < 8; ++nt)
                    orow[nt * 16] = ((acc[mt][nt][reg] - mean) * rstd * wreg[nt] + breg[nt]) * mf;
            }
    }
}

// ---------------------------------------------------------------------------
extern "C" void kernel_launch(void* const* d_in, const int* in_sizes, int n_in,
                              void* d_out, int out_size, void* d_ws, size_t ws_size,
                              hipStream_t stream) {
    const float* query = (const float*)d_in[0];
    const float* value = (const float*)d_in[1];
    const int* mask = (const int*)d_in[2];
    const float* nw = (const float*)d_in[3];
    const float* nb = (const float*)d_in[4];
    float* out = (float*)d_out;

    char* ws = (char*)d_ws;
    const size_t NT = (size_t)BDIM * DDIM * LDIM;   // 131072 elems per transposed mat

    float* Es = (float*)ws;                                       // 4 x 256 KiB
    unsigned short* Vt16 = (unsigned short*)(ws + 4 * (size_t)NE * 4);
    unsigned short* Qt16 = Vt16 + NT;                             // 256 KiB each
    float* Vt32 = (float*)(ws + 4 * (size_t)NE * 4 + 2 * NT * 2); // 512 KiB
    float* Qt32 = Vt32 + NT;                                      // 512 KiB
    // total ws use: 2.5 MiB

    k_transpose<<<dim3(8, 4, 8), 256, 0, stream>>>(query, value, Qt32, Vt32, Qt16, Vt16);
    k_gram_e<<<dim3(8, 4, 4), 128, 0, stream>>>(Qt32, Vt32, mask, Es);
    k_main<<<dim3(4, 32, 4), 256, 0, stream>>>(Es, Vt16, Qt16, mask, nw, nb, out);
}

// Round 2
// 193.169 us; speedup vs baseline: 1.3111x; 1.3111x over previous
//
#include <hip/hip_runtime.h>
#include <hip/hip_bf16.h>
#include <stdint.h>

#define BDIM 4
#define LDIM 128
#define DDIM 256
#define CDIM 512
#define EPSLN 1e-5f
#define NE (BDIM * LDIM * LDIM)
#define SROW 516   // stage row stride (floats): 4*516%32==16 -> 2-way (free) in phase D0

typedef float f32x4 __attribute__((ext_vector_type(4)));
typedef short s16x8 __attribute__((ext_vector_type(8)));
typedef int i32x4 __attribute__((ext_vector_type(4)));

__device__ __forceinline__ unsigned short f2bf(float f) {
    unsigned u = __builtin_bit_cast(unsigned, f);
    u += 0x7fffu + ((u >> 16) & 1u);   // RNE (no NaNs in this data)
    return (unsigned short)(u >> 16);
}

// packed f32x2 -> bf16x2 (v_cvt_pk_bf16_f32 on gfx950), a in low 16, b in high
__device__ __forceinline__ unsigned pk_bf16(float a, float b) {
    union { __hip_bfloat162 h; unsigned u; } cv;
    cv.h = __float22bfloat162_rn(make_float2(a, b));
    return cv.u;
}

// ---------------------------------------------------------------------------
// Fused prep kernel: ONE launch replaces k_transpose + k_gram_e.
//   blockIdx.z < 4  : GRAM duty. (x = i-tile of 16 rows, y = which, z = b)
//     E[which][b][i][k] = exp(0.5*(X[i].Y[k]) - rowmax_unmasked), 0 at masked k.
//     Reads query/value in NATURAL [L][D] layout (no f32 transpose needed):
//     X rows + Y c-tiles staged in LDS; accumulation order per (i,k) is the
//     same ascending-c scalar-FMA sequence as the old k_gram_e -> bit-identical.
//   blockIdx.z >= 4 : TRANSPOSE duty (bf16 only; Qt32/Vt32 deleted).
//     z2 = z-4: b = z2&3, sel = z2>>2, d0 = x*32, k0 = y*32.
// Block 128 threads (2 waves). Grid (8, 4, 12) = 384 blocks.
// ---------------------------------------------------------------------------
__global__ __launch_bounds__(128) void k_prep(const float* __restrict__ query,
                                              const float* __restrict__ value,
                                              const int* __restrict__ mask,
                                              float* __restrict__ Es,
                                              unsigned short* __restrict__ Qt16,
                                              unsigned short* __restrict__ Vt16) {
    // union: gram X_s[16][260] (16640 B) + Y_s[128][68] (34816 B) = 51456 B
    //        transpose tile[32][33] (4224 B) overlays the same space
    __shared__ __align__(16) char smem[16 * 260 * 4 + 128 * 68 * 4];
    float (*X_s)[260] = (float (*)[260])smem;
    float (*Y_s)[68] = (float (*)[68])(smem + 16 * 260 * 4);
    float (*tile)[33] = (float (*)[33])smem;

    const int t = threadIdx.x;

    if (blockIdx.z >= 4) {
        // ---------------- transpose + bf16 cast ----------------
        const int z2 = blockIdx.z - 4;
        const int b = z2 & 3, sel = z2 >> 2;
        const int d0 = blockIdx.x * 32, k0 = blockIdx.y * 32;
        const float* src = sel ? query : value;
        unsigned short* dst16 = sel ? Qt16 : Vt16;
        const int tx = t & 31, ty = t >> 5;   // ty in [0,4)
#pragma unroll
        for (int jj = 0; jj < 8; ++jj) {
            int r = ty + jj * 4;
            tile[r][tx] = src[((size_t)(b * LDIM + k0 + r)) * DDIM + d0 + tx];
        }
        __syncthreads();
#pragma unroll
        for (int jj = 0; jj < 8; ++jj) {
            int r = ty + jj * 4;
            size_t o = ((size_t)(b * DDIM + d0 + r)) * LDIM + k0 + tx;
            dst16[o] = f2bf(tile[tx][r]);
        }
        return;
    }

    // ---------------- gram + E build ----------------
    const int b = blockIdx.z, which = blockIdx.y, it = blockIdx.x;
    const float* X = (which == 0 || which == 2) ? query : value;  // 0:QV 1:VV 2:QQ 3:VQ
    const float* Y = (which <= 1) ? value : query;
    const float* Xb = X + (size_t)b * LDIM * DDIM;
    const float* Yb = Y + (size_t)b * LDIM * DDIM;

    const int i0 = it * 16;
    const int iq = (t >> 5) << 2;     // this thread's 4 i-rows (local)
    const int kl = t & 31;            // k = kl + 32*kk, kk in [0,4)

    // stage X rows [16][256] -> X_s (coalesced: 16 B/lane, consecutive)
#pragma unroll
    for (int u = 0; u < 8; ++u) {
        int ch = u * 128 + t;             // 0..1023 f32x4 chunks
        int row = ch >> 6;                // 64 chunks per 256-f row
        int cc = (ch & 63) << 2;
        *(f32x4*)&X_s[row][cc] = *(const f32x4*)(Xb + (size_t)(i0 + row) * DDIM + cc);
    }

    float acc[4][4] = {};
#pragma unroll 1
    for (int ct = 0; ct < 4; ++ct) {
        // stage Y c-tile [128][64] -> Y_s
#pragma unroll
        for (int u = 0; u < 16; ++u) {
            int ch = u * 128 + t;         // 0..2047 chunks
            int row = ch >> 4;            // 16 chunks per 64-f row
            int cc = (ch & 15) << 2;
            *(f32x4*)&Y_s[row][cc] = *(const f32x4*)(Yb + (size_t)row * DDIM + ct * 64 + cc);
        }
        __syncthreads();
#pragma unroll
        for (int u = 0; u < 16; ++u) {
            const int c = u * 4;
            f32x4 xv[4], yv[4];
#pragma unroll
            for (int ii = 0; ii < 4; ++ii) xv[ii] = *(const f32x4*)&X_s[iq + ii][ct * 64 + c];
#pragma unroll
            for (int kk = 0; kk < 4; ++kk) yv[kk] = *(const f32x4*)&Y_s[kl + 32 * kk][c];
#pragma unroll
            for (int ii = 0; ii < 4; ++ii)
#pragma unroll
                for (int kk = 0; kk < 4; ++kk)
#pragma unroll
                    for (int e = 0; e < 4; ++e)
                        acc[ii][kk] += xv[ii][e] * yv[kk][e];   // ascending-c, bit-identical
        }
        __syncthreads();
    }

    int mk[4];
#pragma unroll
    for (int kk = 0; kk < 4; ++kk) mk[kk] = mask[b * LDIM + kl + 32 * kk];

    float* Eg = Es + (size_t)which * NE + (size_t)b * (LDIM * LDIM);
#pragma unroll
    for (int ii = 0; ii < 4; ++ii) {
        float lg[4];
        float mx = -3.0e38f;
#pragma unroll
        for (int kk = 0; kk < 4; ++kk) {
            lg[kk] = 0.5f * acc[ii][kk];
            if (mk[kk] != 0) mx = fmaxf(mx, lg[kk]);
        }
#pragma unroll
        for (int o = 16; o >= 1; o >>= 1) mx = fmaxf(mx, __shfl_xor(mx, o, 64));
#pragma unroll
        for (int kk = 0; kk < 4; ++kk)
            Eg[(size_t)(i0 + iq + ii) * LDIM + kl + 32 * kk] =
                (mk[kk] != 0) ? __expf(lg[kk] - mx) : 0.0f;
    }
}

// ---------------------------------------------------------------------------
// Main fused kernel.  (REVERTED to the proven v238 structure — the R1 JT=4
// restructure regressed +15 µs.)  grid (4 i-tiles, 128 j, B), block 256
// (4 waves), 1 j/blk.  Wave wv: path = wv>>1 (0: attn@V cols 0..255,
// 1: attn_q@Q cols 256..511), nh = wv&1 (128-col half). B-frags reg-resident.
// Epilogue: acc*zinv -> 32x516 f32 LDS stage (unioned with dead P bufs);
// each wave then owns 8 full rows: shuffle-reduce LN, apply affine+mask,
// store 16 B/lane contiguous (full 128 B lines, plain cached -> no RMW).
// MFMA 16x16x32 bf16: A[m=lane&15][k=quad*8+u], B[k][n=lane&15],
//                     C row = quad*4+reg, col = lane&15.  (verified R1)
// ---------------------------------------------------------------------------
__global__ __launch_bounds__(256, 2) void k_main(const float* __restrict__ E1,
                                                 const unsigned short* __restrict__ Vt16,
                                                 const unsigned short* __restrict__ Qt16,
                                                 const int* __restrict__ mask,
                                                 const float* __restrict__ nw,
                                                 const float* __restrict__ nb,
                                                 float* __restrict__ out) {
    // union: P buffers (17408 B) live inside the 66048 B staging tile
    __shared__ __align__(16) char smem[32 * SROW * 4];
    unsigned short (*P_s)[136] = (unsigned short (*)[136])smem;
    unsigned short (*Pq_s)[136] = (unsigned short (*)[136])(smem + 32 * 136 * 2);
    float (*stage)[SROW] = (float (*)[SROW])smem;
    __shared__ float wln[CDIM], bln[CDIM];
    __shared__ float zinv_s[64];
    __shared__ float maskv[32];

    const int tid = threadIdx.x;
    const int i0 = blockIdx.x * 32;
    const int j = blockIdx.y;
    const int b = blockIdx.z;

    const int lane = tid & 63;
    const int q = lane >> 4;
    const int l15 = lane & 15;
    const int wv = tid >> 6;
    const int path = wv >> 1;
    const int nh = wv & 1;

    const float* E2 = E1 + NE;
    const float* E1q = E1 + 2 * NE;
    const float* E2q = E1 + 3 * NE;

    wln[tid] = nw[tid]; wln[tid + 256] = nw[tid + 256];
    bln[tid] = nb[tid]; bln[tid + 256] = nb[tid + 256];
    if (tid < 32) maskv[tid] = (mask[b * LDIM + i0 + tid] != 0) ? 1.0f : 0.0f;

    // B-fragment preload: this wave's 128-col x 128-k quarter (from L2).
    const unsigned short* bsrc = (path ? Qt16 : Vt16) +
                                 (size_t)b * DDIM * LDIM + (size_t)(nh * 128) * LDIM;
    s16x8 bfr[8][4];
#pragma unroll
    for (int nt = 0; nt < 8; ++nt)
#pragma unroll
        for (int kc = 0; kc < 4; ++kc)
            bfr[nt][kc] = *(const s16x8*)(bsrc + (size_t)(nt * 16 + l15) * LDIM + kc * 32 + q * 8);

    // ---- phase A: P = E1 (.) E2[j] (packed bf16 -> LDS) + f32 Z row sums ----
    {
        const int m = tid >> 3;
        const int k0 = (tid & 7) * 16;
        const float* e1 = E1 + ((size_t)(b * LDIM + i0 + m)) * LDIM + k0;
        const float* e1q = E1q + ((size_t)(b * LDIM + i0 + m)) * LDIM + k0;
        const float* e2 = E2 + ((size_t)(b * LDIM + j)) * LDIM + k0;
        const float* e2q = E2q + ((size_t)(b * LDIM + j)) * LDIM + k0;
        union { unsigned u32[8]; s16x8 v[2]; } tp, tq;
        float s = 0.f, sq = 0.f;
#pragma unroll
        for (int u4 = 0; u4 < 16; u4 += 4) {
            f32x4 a = *(const f32x4*)(e1 + u4);
            f32x4 c = *(const f32x4*)(e2 + u4);
            f32x4 aq = *(const f32x4*)(e1q + u4);
            f32x4 cq = *(const f32x4*)(e2q + u4);
            float p0 = a[0] * c[0], p1 = a[1] * c[1], p2 = a[2] * c[2], p3 = a[3] * c[3];
            float q0 = aq[0] * cq[0], q1 = aq[1] * cq[1], q2 = aq[2] * cq[2], q3 = aq[3] * cq[3];
            s += (p0 + p1) + (p2 + p3);
            sq += (q0 + q1) + (q2 + q3);
            tp.u32[u4 / 2] = pk_bf16(p0, p1);
            tp.u32[u4 / 2 + 1] = pk_bf16(p2, p3);
            tq.u32[u4 / 2] = pk_bf16(q0, q1);
            tq.u32[u4 / 2 + 1] = pk_bf16(q2, q3);
        }
        *(s16x8*)&P_s[m][k0] = tp.v[0];
        *(s16x8*)&P_s[m][k0 + 8] = tp.v[1];
        *(s16x8*)&Pq_s[m][k0] = tq.v[0];
        *(s16x8*)&Pq_s[m][k0 + 8] = tq.v[1];
        s += __shfl_xor(s, 1, 64); s += __shfl_xor(s, 2, 64); s += __shfl_xor(s, 4, 64);
        sq += __shfl_xor(sq, 1, 64); sq += __shfl_xor(sq, 2, 64); sq += __shfl_xor(sq, 4, 64);
        if ((tid & 7) == 0) { zinv_s[m] = 1.0f / s; zinv_s[32 + m] = 1.0f / sq; }
    }
    __syncthreads();

    // ---- phase B: MFMA (B-frags in registers, no staging barriers) ----
    f32x4 acc[2][8];
#pragma unroll
    for (int mt = 0; mt < 2; ++mt)
#pragma unroll
        for (int nt = 0; nt < 8; ++nt) acc[mt][nt] = (f32x4){0.f, 0.f, 0.f, 0.f};

    const unsigned short(*As)[136] = path ? Pq_s : P_s;
#pragma unroll
    for (int kc = 0; kc < 4; ++kc) {
        const s16x8 a0 = *(const s16x8*)&As[l15][kc * 32 + q * 8];
        const s16x8 a1 = *(const s16x8*)&As[16 + l15][kc * 32 + q * 8];
#pragma unroll
        for (int nt = 0; nt < 8; ++nt) {
            acc[0][nt] = __builtin_amdgcn_mfma_f32_16x16x32_bf16(a0, bfr[nt][kc], acc[0][nt], 0, 0, 0);
            acc[1][nt] = __builtin_amdgcn_mfma_f32_16x16x32_bf16(a1, bfr[nt][kc], acc[1][nt], 0, 0, 0);
        }
    }
    __syncthreads();   // all MFMA reads of P done -> P dead, stage may clobber

    // ---- phase D0: normalized values -> stage tile (2-way LDS, free) ----
#pragma unroll
    for (int mt = 0; mt < 2; ++mt) {
#pragma unroll
        for (int reg = 0; reg < 4; ++reg) {
            const int row = mt * 16 + q * 4 + reg;
            const float zv = zinv_s[path * 32 + row];
#pragma unroll
            for (int nt = 0; nt < 8; ++nt) {
                const int c = path * 256 + nh * 128 + nt * 16 + l15;
                stage[row][c] = acc[mt][nt][reg] * zv;
            }
        }
    }
    __syncthreads();

    // ---- phase E: per-wave rows: shuffle-LN + affine + mask + coalesced store
    {
        const f32x4 w0 = *(const f32x4*)&wln[lane * 4];
        const f32x4 b0 = *(const f32x4*)&bln[lane * 4];
        const f32x4 w1 = *(const f32x4*)&wln[256 + lane * 4];
        const f32x4 b1 = *(const f32x4*)&bln[256 + lane * 4];
#pragma unroll
        for (int rr = 0; rr < 8; ++rr) {
            const int row = wv * 8 + rr;
            const f32x4 v0 = *(const f32x4*)&stage[row][lane * 4];
            const f32x4 v1 = *(const f32x4*)&stage[row][256 + lane * 4];
            float s1 = (v0[0] + v0[1]) + (v0[2] + v0[3]) + (v1[0] + v1[1]) + (v1[2] + v1[3]);
            float s2 = (v0[0] * v0[0] + v0[1] * v0[1]) + (v0[2] * v0[2] + v0[3] * v0[3]) +
                       (v1[0] * v1[0] + v1[1] * v1[1]) + (v1[2] * v1[2] + v1[3] * v1[3]);
#pragma unroll
            for (int o = 1; o <= 32; o <<= 1) {
                s1 += __shfl_xor(s1, o, 64);
                s2 += __shfl_xor(s2, o, 64);
            }
            const float mean = s1 * (1.0f / 512.0f);
            const float var = s2 * (1.0f / 512.0f) - mean * mean;
            const float rstd = rsqrtf(var + EPSLN);
            const float mf = maskv[row];
            float* orow = out + (((size_t)(b * LDIM + i0 + row)) * LDIM + j) * CDIM;
            f32x4 o0, o1;
#pragma unroll
            for (int u = 0; u < 4; ++u) {
                o0[u] = ((v0[u] - mean) * rstd * w0[u] + b0[u]) * mf;
                o1[u] = ((v1[u] - mean) * rstd * w1[u] + b1[u]) * mf;
            }
            *(f32x4*)&orow[lane * 4] = o0;
            *(f32x4*)&orow[256 + lane * 4] = o1;
        }
    }
}

// ---------------------------------------------------------------------------
extern "C" void kernel_launch(void* const* d_in, const int* in_sizes, int n_in,
                              void* d_out, int out_size, void* d_ws, size_t ws_size,
                              hipStream_t stream) {
    const float* query = (const float*)d_in[0];
    const float* value = (const float*)d_in[1];
    const int* mask = (const int*)d_in[2];
    const float* nw = (const float*)d_in[3];
    const float* nb = (const float*)d_in[4];
    float* out = (float*)d_out;

    char* ws = (char*)d_ws;
    const size_t NT = (size_t)BDIM * DDIM * LDIM;   // 131072 elems per transposed mat

    float* Es = (float*)ws;                                       // 4 x 256 KiB
    unsigned short* Vt16 = (unsigned short*)(ws + 4 * (size_t)NE * 4);
    unsigned short* Qt16 = Vt16 + NT;                             // 256 KiB each
    // total ws use: 1.5 MiB (Qt32/Vt32 deleted)

    k_prep<<<dim3(8, 4, 12), 128, 0, stream>>>(query, value, mask, Es, Qt16, Vt16);
    k_main<<<dim3(4, 128, 4), 256, 0, stream>>>(Es, Vt16, Qt16, mask, nw, nb, out);
}